// Round 10
// baseline (32.767 us; speedup 1.0000x reference)
//
#include <hip/hip_runtime.h>

// FK over the SMPL joint tree — R9's staging regime (single-wave decoupled
// blocks, many async DMA chunks, one drain) + R7's joint-per-lane
// pointer-doubling compute, looped over 8 frame-pairs to shrink LDS/wave.
//
// Block = 64 threads = 1 wave = 16 frames; LDS = 16*132 f32 = 8448 B
// -> 16 waves/CU (VGPR-capped via __launch_bounds__(64,4), i.e. <=128 VGPR),
// 1.8x R9's TLP. Stage: 8 full 1024B global_load_lds dwordx4 chunks + one
// 256B chunk (lanes 0-15) — zero over-read. Compute: for fp=0..7, lane
// handles joint j=lane&31 of frame 2*fp+(lane>>5); Gram-Schmidt then 3
// pointer-doubling steps A[j] = A[anc_s[j]] @ A[j] (parent / parent^2 /
// parent^4 packed as u64 immediates; step masks j>=1 / j>=4 / j>=10 since
// depth is monotone in joint id) — fully uniform, shuffle-based, no
// barriers. Outputs overwrite input slots in LDS; coalesced b128 store.

#define TPB 64
#define TILE_FRAMES 16
#define TILE_FLOATS (TILE_FRAMES * 132)  // 2112 floats = 8448 B

namespace {
constexpr int PAR1[22] = {0,0,0,0,1,2,3,4,5,6,7,8,9,9,9,12,13,14,16,17,18,19};
constexpr int PAR2[22] = {0,0,0,0,0,0,0,1,2,3,4,5,6,6,6,9,9,9,13,14,16,17};   // par^2
constexpr int PAR4[22] = {0,0,0,0,0,0,0,0,0,0,0,0,0,0,0,3,3,3,6,6,9,9};       // par^4

__device__ __host__ constexpr unsigned long long pack5(const int (&t)[22], int base) {
    unsigned long long v = 0;
    for (int i = 0; i < 11; ++i)
        v |= (unsigned long long)(t[base + i] & 31) << (5 * i);
    return v;
}
constexpr unsigned long long P1L = pack5(PAR1, 0), P1H = pack5(PAR1, 11);
constexpr unsigned long long P2L = pack5(PAR2, 0), P2H = pack5(PAR2, 11);
constexpr unsigned long long P4L = pack5(PAR4, 0), P4H = pack5(PAR4, 11);
}  // namespace

__device__ __forceinline__ void mm3(float* __restrict__ D, const float* __restrict__ P,
                                    const float* __restrict__ L) {
#pragma unroll
    for (int r = 0; r < 3; ++r)
#pragma unroll
        for (int c = 0; c < 3; ++c)
            D[3 * r + c] = P[3 * r + 0] * L[0 + c] +
                           P[3 * r + 1] * L[3 + c] +
                           P[3 * r + 2] * L[6 + c];
}

__global__ __launch_bounds__(TPB, 4) void fk6d_kernel(const float* __restrict__ in,
                                                      float* __restrict__ out)
{
    __shared__ float lds[TILE_FLOATS];  // 8448 B
    const int lane = threadIdx.x;
    const int col = lane >> 5;          // which frame of the pair
    const int base = lane & 32;         // shuffle-group base
    const int j = lane & 31;            // joint id (valid < 22)

    const float* gin = in + (size_t)blockIdx.x * TILE_FLOATS;
    float* gout = out + (size_t)blockIdx.x * TILE_FLOATS;

    // ---- async stage: 8 full 1024B chunks + 256B tail (lanes 0-15)
#pragma unroll
    for (int k = 0; k < 8; ++k)
        __builtin_amdgcn_global_load_lds(
            (const __attribute__((address_space(1))) void*)(gin + k * 256 + lane * 4),
            (__attribute__((address_space(3))) void*)(lds + k * 256), 16, 0, 0);
    if (lane < 16)
        __builtin_amdgcn_global_load_lds(
            (const __attribute__((address_space(1))) void*)(gin + 2048 + lane * 4),
            (__attribute__((address_space(3))) void*)(lds + 2048), 16, 0, 0);
    __syncthreads();  // 1-wave block: vmcnt drain + cheap barrier

    // ---- loop-invariant ancestor lanes
    const bool act = (j < 22);
    const int jc = act ? j : 21;
    const int jm = (jc < 11) ? jc : jc - 11;
    const int sh = 5 * jm;
    const int s1 = base | ((int)(((jc < 11) ? P1L : P1H) >> sh) & 31);
    const int s2 = base | ((int)(((jc < 11) ? P2L : P2H) >> sh) & 31);
    const int s4 = base | ((int)(((jc < 11) ? P4L : P4H) >> sh) & 31);
    const bool on1 = (j >= 1), on2 = (j >= 4), on3 = (j >= 10);

#pragma unroll 2
    for (int fp = 0; fp < 8; ++fp) {
        const int frame = 2 * fp + col;
        float* slot = lds + frame * 132 + j * 6;

        // ---- Gram-Schmidt -> A = local rotation (row-major)
        float A[9];
#pragma unroll
        for (int k = 0; k < 9; ++k) A[k] = 0.0f;
        if (act) {
            float2 d0 = *reinterpret_cast<const float2*>(slot);
            float2 d1 = *reinterpret_cast<const float2*>(slot + 2);
            float2 d2 = *reinterpret_cast<const float2*>(slot + 4);
            float a1x = d0.x, a1y = d0.y, a1z = d1.x;
            float a2x = d1.y, a2y = d2.x, a2z = d2.y;
            float n1 = sqrtf(a1x * a1x + a1y * a1y + a1z * a1z);
            float i1 = 1.0f / fmaxf(n1, 1e-12f);
            float b1x = a1x * i1, b1y = a1y * i1, b1z = a1z * i1;
            float dt = b1x * a2x + b1y * a2y + b1z * a2z;
            float cx = a2x - dt * b1x, cy = a2y - dt * b1y, cz = a2z - dt * b1z;
            float n2 = sqrtf(cx * cx + cy * cy + cz * cz);
            float i2 = 1.0f / fmaxf(n2, 1e-12f);
            A[0] = b1x; A[1] = b1y; A[2] = b1z;
            A[3] = cx * i2; A[4] = cy * i2; A[5] = cz * i2;
            A[6] = A[1] * A[5] - A[2] * A[4];
            A[7] = A[2] * A[3] - A[0] * A[5];
            A[8] = A[0] * A[4] - A[1] * A[3];
        }

        // ---- pointer-doubling (uniform, no barriers)
        {
            float M[9], T[9];
#pragma unroll
            for (int k = 0; k < 9; ++k) M[k] = __shfl(A[k], s1, 64);
            mm3(T, M, A);
#pragma unroll
            for (int k = 0; k < 9; ++k) A[k] = on1 ? T[k] : A[k];
        }
        {
            float M[9], T[9];
#pragma unroll
            for (int k = 0; k < 9; ++k) M[k] = __shfl(A[k], s2, 64);
            mm3(T, M, A);
#pragma unroll
            for (int k = 0; k < 9; ++k) A[k] = on2 ? T[k] : A[k];
        }
        {
            float M[9], T[9];
#pragma unroll
            for (int k = 0; k < 9; ++k) M[k] = __shfl(A[k], s4, 64);
            mm3(T, M, A);
#pragma unroll
            for (int k = 0; k < 9; ++k) A[k] = on3 ? T[k] : A[k];
        }

        // ---- write rows 0..1 back in place
        if (act) {
            *reinterpret_cast<float2*>(slot)     = make_float2(A[0], A[1]);
            *reinterpret_cast<float2*>(slot + 2) = make_float2(A[2], A[3]);
            *reinterpret_cast<float2*>(slot + 4) = make_float2(A[4], A[5]);
        }
    }
    __syncthreads();  // 1-wave: LDS-write ordering before store reads

    // ---- coalesced store: 8 full float4 rounds + 16-lane tail
    const float4* l4 = reinterpret_cast<const float4*>(lds);
    float4* o4 = reinterpret_cast<float4*>(gout);
#pragma unroll
    for (int k = 0; k < 8; ++k) o4[k * 64 + lane] = l4[k * 64 + lane];
    if (lane < 16) o4[512 + lane] = l4[512 + lane];
}

// scalar tail (not taken for 512x196: 100352 % 16 == 0)
__global__ void fk6d_tail(const float* __restrict__ in, float* __restrict__ out,
                          int n0, int N) {
    constexpr int PAR[22] = {0, 0, 0, 0, 1, 2, 3, 4, 5, 6, 7, 8, 9, 9, 9,
                             12, 13, 14, 16, 17, 18, 19};
    int n = n0 + blockIdx.x * blockDim.x + threadIdx.x;
    if (n >= N) return;
    const float* src = in + (size_t)n * 132;
    float* dst = out + (size_t)n * 132;
    float Rg[22][9];
#pragma unroll
    for (int jj = 0; jj < 22; ++jj) {
        const float* s = src + 6 * jj;
        float Lr[9];
        float n1 = sqrtf(s[0]*s[0] + s[1]*s[1] + s[2]*s[2]);
        float i1 = 1.0f / fmaxf(n1, 1e-12f);
        float b1x = s[0]*i1, b1y = s[1]*i1, b1z = s[2]*i1;
        float dt = b1x*s[3] + b1y*s[4] + b1z*s[5];
        float cx = s[3]-dt*b1x, cy = s[4]-dt*b1y, cz = s[5]-dt*b1z;
        float n2 = sqrtf(cx*cx + cy*cy + cz*cz);
        float i2 = 1.0f / fmaxf(n2, 1e-12f);
        Lr[0]=b1x; Lr[1]=b1y; Lr[2]=b1z;
        Lr[3]=cx*i2; Lr[4]=cy*i2; Lr[5]=cz*i2;
        Lr[6]=Lr[1]*Lr[5]-Lr[2]*Lr[4];
        Lr[7]=Lr[2]*Lr[3]-Lr[0]*Lr[5];
        Lr[8]=Lr[0]*Lr[4]-Lr[1]*Lr[3];
        if (jj == 0) {
#pragma unroll
            for (int k = 0; k < 9; ++k) Rg[0][k] = Lr[k];
        } else {
            mm3(Rg[jj], Rg[PAR[jj]], Lr);
        }
#pragma unroll
        for (int k = 0; k < 6; ++k) dst[6 * jj + k] = Rg[jj][k];
    }
}

extern "C" void kernel_launch(void* const* d_in, const int* in_sizes, int n_in,
                              void* d_out, int out_size, void* d_ws, size_t ws_size,
                              hipStream_t stream) {
    const float* in = (const float*)d_in[0];
    float* out = (float*)d_out;
    int N = in_sizes[0] / 132;        // 100352 frames
    int NT = N / TILE_FRAMES;         // 6272 full tiles
    if (NT > 0) fk6d_kernel<<<NT, TPB, 0, stream>>>(in, out);
    int rem = N - NT * TILE_FRAMES;
    if (rem > 0)
        fk6d_tail<<<(rem + 63) / 64, 64, 0, stream>>>(in, out, NT * TILE_FRAMES, N);
}

// Round 11
// 24.933 us; speedup vs baseline: 1.3142x; 1.3142x over previous
//
#include <hip/hip_runtime.h>

// FK over the SMPL joint tree — R9 structure with a 28-frame tile for
// higher occupancy. Block = 64 threads = 1 wave = 28 frames; LDS = 14784 B
// -> 11 blocks/CU (vs R9's 9), VGPR cap (~132 regs -> ~15 waves/CU) not
// binding. 28 | 100352 -> 3584 blocks, no tail launch.
// Stage: 14 async 1024B global_load_lds dwordx4 chunks + one 448B chunk
// (lanes 0-27) — zero over-read. Compute: lane l -> frame fi=l&31 (<28),
// half h=l>>5 (h=0: joints 0-10, h=1: joints 11-21). Gram-Schmidt is
// lane-uniform (11 joints/lane); Rg[8],Rg[9] hand off A->B via
// __shfl_xor(.,32); exec-masked half-chains. Outputs overwrite the frame's
// input slots in LDS; coalesced b128 store (14 rounds + 28-lane tail).

#define TPB 64
#define TILE_FRAMES 28
#define TILE_FLOATS (TILE_FRAMES * 132)  // 3696 floats = 14784 B

__device__ __forceinline__ void local_rot(const float* s, float* L) {
    float a1x = s[0], a1y = s[1], a1z = s[2];
    float a2x = s[3], a2y = s[4], a2z = s[5];
    float n1 = sqrtf(a1x * a1x + a1y * a1y + a1z * a1z);
    float i1 = 1.0f / fmaxf(n1, 1e-12f);
    float b1x = a1x * i1, b1y = a1y * i1, b1z = a1z * i1;
    float dt = b1x * a2x + b1y * a2y + b1z * a2z;
    float cx = a2x - dt * b1x, cy = a2y - dt * b1y, cz = a2z - dt * b1z;
    float n2 = sqrtf(cx * cx + cy * cy + cz * cz);
    float i2 = 1.0f / fmaxf(n2, 1e-12f);
    L[0] = b1x; L[1] = b1y; L[2] = b1z;
    L[3] = cx * i2; L[4] = cy * i2; L[5] = cz * i2;
    L[6] = L[1] * L[5] - L[2] * L[4];
    L[7] = L[2] * L[3] - L[0] * L[5];
    L[8] = L[0] * L[4] - L[1] * L[3];
}

__device__ __forceinline__ void matmul3(float* G, const float* P, const float* L) {
#pragma unroll
    for (int r = 0; r < 3; ++r)
#pragma unroll
        for (int c = 0; c < 3; ++c)
            G[3 * r + c] = P[3 * r + 0] * L[0 + c] +
                           P[3 * r + 1] * L[3 + c] +
                           P[3 * r + 2] * L[6 + c];
}

__global__ __launch_bounds__(TPB) void fk6d_kernel(const float* __restrict__ in,
                                                   float* __restrict__ out)
{
    __shared__ float lds[TILE_FLOATS];  // 14784 B -> 11 blocks/CU
    const int lane = threadIdx.x;
    const int half = lane >> 5;      // 0: joints 0-10, 1: joints 11-21
    const int fi = lane & 31;        // frame index (valid < 28)
    const bool act = (fi < TILE_FRAMES);

    const float* gin = in + (size_t)blockIdx.x * TILE_FLOATS;
    float* gout = out + (size_t)blockIdx.x * TILE_FLOATS;

    // ---- async stage: 14 full 1024B chunks + 448B tail (lanes 0-27)
#pragma unroll
    for (int k = 0; k < 14; ++k)
        __builtin_amdgcn_global_load_lds(
            (const __attribute__((address_space(1))) void*)(gin + k * 256 + lane * 4),
            (__attribute__((address_space(3))) void*)(lds + k * 256), 16, 0, 0);
    if (lane < TILE_FRAMES)
        __builtin_amdgcn_global_load_lds(
            (const __attribute__((address_space(1))) void*)(gin + 3584 + lane * 4),
            (__attribute__((address_space(3))) void*)(lds + 3584), 16, 0, 0);
    __syncthreads();  // 1-wave block: vmcnt drain + cheap barrier

    float* base = lds + fi * 132;
    const float* src = base + 66 * half;

    // ---- phase 1 (uniform): Gram-Schmidt for this lane's 11 joints
    float L[11][9];
    if (act) {
#pragma unroll
        for (int i = 0; i < 11; ++i) local_rot(src + 6 * i, L[i]);
    }

    // ---- phase 2 (half A): chain joints 0-10, write outs, extract Rg8/Rg9
    float e8[9], e9[9];
    if (act && half == 0) {
        float Rg[11][9];
#pragma unroll
        for (int k = 0; k < 9; ++k) Rg[0][k] = L[0][k];
        matmul3(Rg[1], Rg[0], L[1]);
        matmul3(Rg[2], Rg[0], L[2]);
        matmul3(Rg[3], Rg[0], L[3]);
        matmul3(Rg[4], Rg[1], L[4]);
        matmul3(Rg[5], Rg[2], L[5]);
        matmul3(Rg[6], Rg[3], L[6]);
        matmul3(Rg[7], Rg[4], L[7]);
        matmul3(Rg[8], Rg[5], L[8]);
        matmul3(Rg[9], Rg[6], L[9]);
        matmul3(Rg[10], Rg[7], L[10]);
#pragma unroll
        for (int i = 0; i < 11; ++i)
#pragma unroll
            for (int k = 0; k < 6; ++k) base[6 * i + k] = Rg[i][k];
#pragma unroll
        for (int k = 0; k < 9; ++k) { e8[k] = Rg[8][k]; e9[k] = Rg[9][k]; }
    }

    // ---- phase 3 (uniform): hand Rg8/Rg9 from lanes l to lanes l+32
#pragma unroll
    for (int k = 0; k < 9; ++k) {
        e8[k] = __shfl_xor(e8[k], 32, 64);
        e9[k] = __shfl_xor(e9[k], 32, 64);
    }

    // ---- phase 4 (half B): chain joints 11-21, write outs
    if (act && half == 1) {
        float Rg[11][9];  // local idx i = joint 11+i
        matmul3(Rg[0], e8, L[0]);       // j11 <- j8
        matmul3(Rg[1], e9, L[1]);       // j12 <- j9
        matmul3(Rg[2], e9, L[2]);       // j13 <- j9
        matmul3(Rg[3], e9, L[3]);       // j14 <- j9
        matmul3(Rg[4], Rg[1], L[4]);    // j15 <- j12
        matmul3(Rg[5], Rg[2], L[5]);    // j16 <- j13
        matmul3(Rg[6], Rg[3], L[6]);    // j17 <- j14
        matmul3(Rg[7], Rg[5], L[7]);    // j18 <- j16
        matmul3(Rg[8], Rg[6], L[8]);    // j19 <- j17
        matmul3(Rg[9], Rg[7], L[9]);    // j20 <- j18
        matmul3(Rg[10], Rg[8], L[10]);  // j21 <- j19
#pragma unroll
        for (int i = 0; i < 11; ++i)
#pragma unroll
            for (int k = 0; k < 6; ++k) base[66 + 6 * i + k] = Rg[i][k];
    }
    __syncthreads();  // 1-wave: LDS-write ordering before store reads

    // ---- coalesced store: 14 full float4 rounds + 28-lane tail
    const float4* l4 = reinterpret_cast<const float4*>(lds);
    float4* o4 = reinterpret_cast<float4*>(gout);
#pragma unroll
    for (int k = 0; k < 14; ++k) o4[k * 64 + lane] = l4[k * 64 + lane];
    if (lane < TILE_FRAMES) o4[896 + lane] = l4[896 + lane];
}

// scalar tail (not taken: 100352 % 28 == 0)
__global__ void fk6d_tail(const float* __restrict__ in, float* __restrict__ out,
                          int n0, int N) {
    constexpr int PAR[22] = {0, 0, 0, 0, 1, 2, 3, 4, 5, 6, 7, 8, 9, 9, 9,
                             12, 13, 14, 16, 17, 18, 19};
    int n = n0 + blockIdx.x * blockDim.x + threadIdx.x;
    if (n >= N) return;
    const float* src = in + (size_t)n * 132;
    float* dst = out + (size_t)n * 132;
    float Rg[22][9];
#pragma unroll
    for (int j = 0; j < 22; ++j) {
        float Lr[9];
        local_rot(src + 6 * j, Lr);
        if (j == 0) {
#pragma unroll
            for (int k = 0; k < 9; ++k) Rg[0][k] = Lr[k];
        } else {
            matmul3(Rg[j], Rg[PAR[j]], Lr);
        }
#pragma unroll
        for (int k = 0; k < 6; ++k) dst[6 * j + k] = Rg[j][k];
    }
}

extern "C" void kernel_launch(void* const* d_in, const int* in_sizes, int n_in,
                              void* d_out, int out_size, void* d_ws, size_t ws_size,
                              hipStream_t stream) {
    const float* in = (const float*)d_in[0];
    float* out = (float*)d_out;
    int N = in_sizes[0] / 132;        // 100352 frames
    int NT = N / TILE_FRAMES;         // 3584 full tiles
    if (NT > 0) fk6d_kernel<<<NT, TPB, 0, stream>>>(in, out);
    int rem = N - NT * TILE_FRAMES;
    if (rem > 0)
        fk6d_tail<<<(rem + 63) / 64, 64, 0, stream>>>(in, out, NT * TILE_FRAMES, N);
}